// Round 1
// baseline (604.940 us; speedup 1.0000x reference)
//
#include <hip/hip_runtime.h>
#include <cmath>

typedef __bf16  v8bf  __attribute__((ext_vector_type(8)));
typedef float   v4f   __attribute__((ext_vector_type(4)));

#define HH 56
#define WW2 56
#define SS 3
#define HEADS 6
#define DIM 192
#define HID 768
#define NTOK 49
#define NWIN 2048            // BATCH * 64
#define MTOT (NWIN * NTOK)   // 100352
#define SCALE 0.17677669529663687f

// async global->LDS, 16B per lane. LDS dest must be wave-uniform base + lane*16.
__device__ __forceinline__ void async_cp16(const __bf16* g, __bf16* l) {
    __builtin_amdgcn_global_load_lds(
        (const __attribute__((address_space(1))) void*)g,
        (__attribute__((address_space(3))) void*)l,
        16, 0, 0);
}

// ---------------------------------------------------------------------------
// Weight transpose + f32->bf16 cast: out[n*K + k] = (bf16)in[k*N + n]
// ---------------------------------------------------------------------------
__global__ void k_transpose(const float* __restrict__ in, __bf16* __restrict__ out,
                            int K, int N) {
    int idx = blockIdx.x * 256 + threadIdx.x;
    if (idx >= K * N) return;
    int n = idx / K, k = idx - n * K;
    out[idx] = (__bf16)in[k * N + n];
}

// ---------------------------------------------------------------------------
// Precompute bias tables: bias_tab[type][h][m][n], type in {0=interior,
// 1=right-edge, 2=bottom-edge, 3=corner}. Includes rel-pos bias, shift mask,
// and -1e9 padding for cols m>=49.  n-contiguous so attention loads float4.
// ---------------------------------------------------------------------------
__global__ void k_bias(const float* __restrict__ rpb, float* __restrict__ bt) {
    int type = blockIdx.x, h = blockIdx.y;
    for (int idx = threadIdx.x; idx < 4096; idx += 256) {
        int m = idx >> 6, n = idx & 63;
        float v;
        if (m >= 49) v = -1e9f;
        else if (n >= 49) v = 0.f;
        else {
            int ni = n / 7, nj = n % 7, mi = m / 7, mj = m % 7;
            v = rpb[((ni - mi + 6) * 13 + (nj - mj + 6)) * 6 + h];
            int rin = (type & 2) ? ((ni < 4) ? 1 : 2) : 0;
            int rjn = (type & 1) ? ((nj < 4) ? 1 : 2) : 0;
            int rim = (type & 2) ? ((mi < 4) ? 1 : 2) : 0;
            int rjm = (type & 1) ? ((mj < 4) ? 1 : 2) : 0;
            if (rin * 3 + rjn != rim * 3 + rjm) v -= 100.f;
        }
        bt[((size_t)(type * HEADS + h) * 64 + m) * 64 + n] = v;
    }
}

// ---------------------------------------------------------------------------
// LN1 + cyclic shift(-3,-3) + window partition. x f32 -> xw bf16 [w*49+p][c].
// ---------------------------------------------------------------------------
__global__ __launch_bounds__(256) void k_ln1win(const float* __restrict__ x,
                                                const float* __restrict__ g,
                                                const float* __restrict__ bt,
                                                __bf16* __restrict__ xw) {
    int wv = threadIdx.x >> 6, lane = threadIdx.x & 63;
    int t = blockIdx.x * 4 + wv;
    int w = t / NTOK, p = t - w * NTOK;
    int b = w >> 6, wi = w & 63;
    int i = (wi >> 3) * 7 + p / 7;
    int j = (wi & 7) * 7 + p % 7;
    int io = i + SS; if (io >= HH) io -= HH;
    int jo = j + SS; if (jo >= WW2) jo -= WW2;
    const float* src = x + ((size_t)(b * 3136 + io * 56 + jo)) * DIM;
    float v0 = src[lane], v1 = src[lane + 64], v2 = src[lane + 128];
    float s = v0 + v1 + v2, s2 = v0 * v0 + v1 * v1 + v2 * v2;
    #pragma unroll
    for (int off = 1; off < 64; off <<= 1) {
        s  += __shfl_xor(s, off);
        s2 += __shfl_xor(s2, off);
    }
    float mu = s * (1.f / 192.f);
    float rstd = rsqrtf(s2 * (1.f / 192.f) - mu * mu + 1e-5f);
    __bf16* dst = xw + (size_t)t * DIM;
    dst[lane]       = (__bf16)((v0 - mu) * rstd * g[lane]       + bt[lane]);
    dst[lane + 64]  = (__bf16)((v1 - mu) * rstd * g[lane + 64]  + bt[lane + 64]);
    dst[lane + 128] = (__bf16)((v2 - mu) * rstd * g[lane + 128] + bt[lane + 128]);
}

// ---------------------------------------------------------------------------
// 128x128-tile MFMA GEMM: C = A[MxK] * Wt[NxK]^T + bias.
// MODE 0: qkv scatter -> qb/kb/vb [w,h,t,32] bf16 (q scaled); kb/vb derived.
// MODE 1: proj -> outf = x1 (window-reverse scatter) + xres, f32
// ---------------------------------------------------------------------------
template<int KDIM, int NDIM, int MODE>
__global__ __launch_bounds__(256) void k_gemm128(const __bf16* __restrict__ A,
                                                 const __bf16* __restrict__ Wt,
                                                 const float* __restrict__ bias,
                                                 __bf16* __restrict__ outb,
                                                 const float* __restrict__ x1in,
                                                 float* __restrict__ outf,
                                                 const float* __restrict__ xres) {
    __shared__ __bf16 lA[128 * 32];
    __shared__ __bf16 lB[128 * 32];
    const int tid = threadIdx.x;
    const int m0 = blockIdx.x * 128, n0 = blockIdx.y * 128;
    const int wv = tid >> 6, lane = tid & 63;
    const int wm = (wv >> 1) * 64, wn = (wv & 1) * 64;
    const int lrow = lane & 15, lq = lane >> 4;
    const int grow = tid >> 2, gkc = (tid & 3) * 8;
    v4f acc[4][4] = {};
    for (int kk = 0; kk < KDIM; kk += 32) {
        #pragma unroll
        for (int c = 0; c < 2; c++) {
            int r = grow + c * 64;
            async_cp16(A + (size_t)(m0 + r) * KDIM + kk + gkc, lA + tid * 8 + c * 2048);
            int rb = n0 + r;
            if (NDIM % 128) rb = (rb < NDIM) ? rb : (NDIM - 1);
            async_cp16(Wt + (size_t)rb * KDIM + kk + gkc, lB + tid * 8 + c * 2048);
        }
        __syncthreads();
        v8bf af[4], bf[4];
        #pragma unroll
        for (int i = 0; i < 4; i++) {
            af[i] = *(const v8bf*)(lA + (wm + i * 16 + lrow) * 32 + lq * 8);
            bf[i] = *(const v8bf*)(lB + (wn + i * 16 + lrow) * 32 + lq * 8);
        }
        #pragma unroll
        for (int i = 0; i < 4; i++)
        #pragma unroll
        for (int j = 0; j < 4; j++)
            acc[i][j] = __builtin_amdgcn_mfma_f32_16x16x32_bf16(af[i], bf[j], acc[i][j], 0, 0, 0);
        __syncthreads();
    }
    #pragma unroll
    for (int i = 0; i < 4; i++)
    #pragma unroll
    for (int j = 0; j < 4; j++) {
        int col = n0 + wn + j * 16 + lrow;
        if (NDIM % 128 && col >= NDIM) continue;
        float bv = bias[col];
        #pragma unroll
        for (int r = 0; r < 4; r++) {
            int row = m0 + wm + i * 16 + lq * 4 + r;
            float v = acc[i][j][r] + bv;
            if (MODE == 0) {
                __bf16* kbp = outb + (size_t)MTOT * DIM;
                __bf16* vbp = kbp + (size_t)MTOT * DIM;
                int which = col / DIM, rem = col - which * DIM;
                int hh = rem >> 5, d = rem & 31;
                int w = row / NTOK, p = row - w * NTOK;
                size_t off = ((size_t)(w * HEADS + hh) * NTOK + p) * 32 + d;
                if (which == 0)      outb[off] = (__bf16)(v * SCALE);
                else if (which == 1) kbp[off] = (__bf16)v;
                else                 vbp[off] = (__bf16)v;
            } else {  // proj: window-reverse + unshift + residual
                int w = row / NTOK, p = row - w * NTOK;
                int bimg = w >> 6, wi = w & 63;
                int ii = (wi >> 3) * 7 + p / 7;
                int jj = (wi & 7) * 7 + p % 7;
                int io = ii + SS; if (io >= HH) io -= HH;
                int jo = jj + SS; if (jo >= WW2) jo -= WW2;
                size_t o = ((size_t)(bimg * 3136 + io * 56 + jo)) * DIM + col;
                outf[o] = v + xres[o];
            }
        }
    }
}

// ---------------------------------------------------------------------------
// MFMA windowed attention: one wave per (window, head), 64-thread blocks.
// ---------------------------------------------------------------------------
__global__ __launch_bounds__(64) void k_attn_mfma(const __bf16* __restrict__ qb,
                                                  const float* __restrict__ bias_tab,
                                                  __bf16* __restrict__ ao) {
    __shared__ __bf16 Pl[64 * 72];
    __shared__ __bf16 VTl[32 * 72];
    const __bf16* kb = qb + (size_t)MTOT * DIM;
    const __bf16* vb = kb + (size_t)MTOT * DIM;
    int wh = blockIdx.x;
    int w = wh / HEADS, h = wh - w * HEADS;
    int lane = threadIdx.x & 63;
    int c = lane & 15, q = lane >> 4;
    const size_t base = (size_t)wh * (NTOK * 32);

    for (int idx = lane; idx < 32 * 16; idx += 64)
        VTl[(idx >> 4) * 72 + 48 + (idx & 15)] = (__bf16)0.f;
    #pragma unroll
    for (int it = 0; it < 4; it++) {
        int idx = it * 64 + lane;
        if (idx < NTOK * 4) {
            int t = idx >> 2, d0 = (idx & 3) * 8;
            v8bf vv = *(const v8bf*)(vb + base + t * 32 + d0);
            #pragma unroll
            for (int ii = 0; ii < 8; ii++) VTl[(d0 + ii) * 72 + t] = vv[ii];
        }
    }
    v8bf af[4], bf[4];
    #pragma unroll
    for (int rt = 0; rt < 4; rt++) {
        int t = rt * 16 + c; t = (t > 48) ? 48 : t;
        af[rt] = *(const v8bf*)(qb + base + t * 32 + q * 8);
        bf[rt] = *(const v8bf*)(kb + base + t * 32 + q * 8);
    }
    v4f S[4][4] = {};
    #pragma unroll
    for (int rt = 0; rt < 4; rt++)
    #pragma unroll
    for (int ct = 0; ct < 4; ct++)
        S[rt][ct] = __builtin_amdgcn_mfma_f32_16x16x32_bf16(af[rt], bf[ct], S[rt][ct], 0, 0, 0);
    int wi = w & 63;
    int type = (((wi >> 3) == 7) ? 2 : 0) + (((wi & 7) == 7) ? 1 : 0);
    const float* bt = bias_tab + (size_t)(type * HEADS + h) * 4096;
    #pragma unroll
    for (int rt = 0; rt < 4; rt++)
    #pragma unroll
    for (int ct = 0; ct < 4; ct++) {
        v4f bv = *(const v4f*)(bt + (ct * 16 + c) * 64 + rt * 16 + q * 4);
        S[rt][ct] += bv;
    }
    v4f mx4[4], inv4[4];
    #pragma unroll
    for (int rt = 0; rt < 4; rt++) {
        v4f m;
        #pragma unroll
        for (int r = 0; r < 4; r++)
            m[r] = fmaxf(fmaxf(S[rt][0][r], S[rt][1][r]), fmaxf(S[rt][2][r], S[rt][3][r]));
        #pragma unroll
        for (int off = 1; off < 16; off <<= 1) {
            #pragma unroll
            for (int r = 0; r < 4; r++) m[r] = fmaxf(m[r], __shfl_xor(m[r], off));
        }
        mx4[rt] = m;
    }
    #pragma unroll
    for (int rt = 0; rt < 4; rt++) {
        v4f dsum = {};
        #pragma unroll
        for (int ct = 0; ct < 4; ct++) {
            #pragma unroll
            for (int r = 0; r < 4; r++) {
                float e = __expf(S[rt][ct][r] - mx4[rt][r]);
                dsum[r] += e;
                Pl[(rt * 16 + q * 4 + r) * 72 + ct * 16 + c] = (__bf16)e;
            }
        }
        #pragma unroll
        for (int off = 1; off < 16; off <<= 1) {
            #pragma unroll
            for (int r = 0; r < 4; r++) dsum[r] += __shfl_xor(dsum[r], off);
        }
        #pragma unroll
        for (int r = 0; r < 4; r++) inv4[rt][r] = 1.f / dsum[r];
    }
    __syncthreads();
    v4f O[4][2] = {};
    #pragma unroll
    for (int k2 = 0; k2 < 2; k2++) {
        v8bf pa[4], pb[2];
        #pragma unroll
        for (int rt = 0; rt < 4; rt++)
            pa[rt] = *(const v8bf*)(Pl + (rt * 16 + c) * 72 + k2 * 32 + q * 8);
        #pragma unroll
        for (int ct = 0; ct < 2; ct++)
            pb[ct] = *(const v8bf*)(VTl + (ct * 16 + c) * 72 + k2 * 32 + q * 8);
        #pragma unroll
        for (int rt = 0; rt < 4; rt++)
        #pragma unroll
        for (int ct = 0; ct < 2; ct++)
            O[rt][ct] = __builtin_amdgcn_mfma_f32_16x16x32_bf16(pa[rt], pb[ct], O[rt][ct], 0, 0, 0);
    }
    __bf16* aop = ao + (size_t)(w * NTOK) * DIM + h * 32;
    #pragma unroll
    for (int rt = 0; rt < 4; rt++)
    #pragma unroll
    for (int r = 0; r < 4; r++) {
        int row = rt * 16 + q * 4 + r;
        if (row < NTOK) {
            #pragma unroll
            for (int ct = 0; ct < 2; ct++)
                aop[(size_t)row * DIM + ct * 16 + c] = (__bf16)(O[rt][ct][r] * inv4[rt][r]);
        }
    }
}

// ---------------------------------------------------------------------------
// Fused MLP: LN2 + fc1 + GELU + fc2 + residual, one kernel, one block = 128
// rows. hid never touches global memory (stays in LDS); a2 never exists.
//
// LDS (131072 B, 1 block/CU):
//   aT: [128 rows][192 bf16], stride 384 B, XOR-swizzled (byte ^= (row&7)<<4)
//   lW: reused: fc1 chunk [128][192] stride 384 B / fc2 chunk [192][128]
//       stride 256 B, both XOR-swizzled (staged via registers -> ds_write_b128)
//   lH: hid chunk [128 rows][128 bf16], stride 256 B, XOR-swizzled
// Swizzle makes all ds_read_b128 fragment reads bank-conflict-free (T2).
// 6 hidden chunks of 128; fc2 output accumulates in registers (4x6 v4f/wave).
// ---------------------------------------------------------------------------
__global__ __launch_bounds__(256, 1) void k_mlp_fused(
        const float* __restrict__ x1,
        const float* __restrict__ n2g, const float* __restrict__ n2b,
        const __bf16* __restrict__ fc1T, const float* __restrict__ fc1b,
        const __bf16* __restrict__ fc2T, const float* __restrict__ fc2b,
        float* __restrict__ out) {
    __shared__ __align__(16) char sm[131072];
    char* aT = sm;               // 49152 B
    char* lW = sm + 49152;       // 49152 B
    char* lH = sm + 98304;       // 32768 B
    const int tid = threadIdx.x;
    const int wv = tid >> 6, lane = tid & 63;
    const int lrow = lane & 15, lq = lane >> 4;
    const int m0 = blockIdx.x * 128;

    // ---- Phase 0: LN2 of 128 rows into aT (bf16, swizzled) ----
    {
        float g0 = n2g[lane], g1 = n2g[lane + 64], g2 = n2g[lane + 128];
        float b0 = n2b[lane], b1 = n2b[lane + 64], b2 = n2b[lane + 128];
        #pragma unroll 4
        for (int it = 0; it < 32; ++it) {
            int row = wv * 32 + it;
            const float* src = x1 + (size_t)(m0 + row) * DIM;
            float v0 = src[lane], v1 = src[lane + 64], v2 = src[lane + 128];
            float s = v0 + v1 + v2, s2 = v0 * v0 + v1 * v1 + v2 * v2;
            #pragma unroll
            for (int off = 1; off < 64; off <<= 1) {
                s  += __shfl_xor(s, off);
                s2 += __shfl_xor(s2, off);
            }
            float mu = s * (1.f / 192.f);
            float rstd = rsqrtf(s2 * (1.f / 192.f) - mu * mu + 1e-5f);
            char* rb = aT + row * 384;
            int xo = (row & 7) << 4;
            *(__bf16*)(rb + ((lane * 2)        ^ xo)) = (__bf16)((v0 - mu) * rstd * g0 + b0);
            *(__bf16*)(rb + ((lane * 2 + 128)  ^ xo)) = (__bf16)((v1 - mu) * rstd * g1 + b1);
            *(__bf16*)(rb + ((lane * 2 + 256)  ^ xo)) = (__bf16)((v2 - mu) * rstd * g2 + b2);
        }
    }
    __syncthreads();

    const int wm  = (wv >> 1) * 64;   // row-tile base (fc1 & fc2)
    const int wc1 = (wv & 1) * 64;    // fc1 col base within 128-chunk
    const int wn  = (wv & 1) * 96;    // fc2 col base (192 total)
    v4f oacc[4][6] = {};

    for (int hc = 0; hc < 6; ++hc) {
        // ---- stage B1 = fc1T[hc*128 .. +128][0..192) into lW (swizzled) ----
        {
            v8bf wbuf[12];
            #pragma unroll
            for (int c = 0; c < 12; ++c) {
                int cid = c * 256 + tid;
                int row = cid / 24, k8 = cid - row * 24;
                wbuf[c] = *(const v8bf*)(fc1T + (size_t)(hc * 128 + row) * 192 + k8 * 8);
            }
            #pragma unroll
            for (int c = 0; c < 12; ++c) {
                int cid = c * 256 + tid;
                int row = cid / 24, k8 = cid - row * 24;
                *(v8bf*)(lW + row * 384 + ((k8 * 16) ^ ((row & 7) << 4))) = wbuf[c];
            }
        }
        __syncthreads();
        // ---- fc1: hid_chunk[128][128] = aT[128x192] * B1^T ----
        v4f hacc[4][4] = {};
        #pragma unroll
        for (int ks = 0; ks < 6; ++ks) {
            v8bf af[4], bw[4];
            #pragma unroll
            for (int i = 0; i < 4; ++i) {
                int ra = wm + i * 16 + lrow;
                af[i] = *(const v8bf*)(aT + ra * 384 + ((ks * 64 + lq * 16) ^ ((ra & 7) << 4)));
                int rw = wc1 + i * 16 + lrow;
                bw[i] = *(const v8bf*)(lW + rw * 384 + ((ks * 64 + lq * 16) ^ ((rw & 7) << 4)));
            }
            #pragma unroll
            for (int i = 0; i < 4; ++i)
            #pragma unroll
            for (int j = 0; j < 4; ++j)
                hacc[i][j] = __builtin_amdgcn_mfma_f32_16x16x32_bf16(af[i], bw[j], hacc[i][j], 0, 0, 0);
        }
        // ---- bias + GELU -> lH (swizzled); prev-hc lH readers done (loop-end barrier)
        #pragma unroll
        for (int i = 0; i < 4; ++i)
        #pragma unroll
        for (int j = 0; j < 4; ++j) {
            float bv = fc1b[hc * 128 + wc1 + j * 16 + lrow];
            #pragma unroll
            for (int r = 0; r < 4; ++r) {
                int row = wm + i * 16 + lq * 4 + r;
                int col = wc1 + j * 16 + lrow;
                float hv = hacc[i][j][r] + bv;
                float ge = 0.5f * hv * (1.f + erff(hv * 0.70710678118654752f));
                *(__bf16*)(lH + row * 256 + ((col * 2) ^ ((row & 7) << 4))) = (__bf16)ge;
            }
        }
        __syncthreads();   // lH visible; all lW (B1) reads complete
        // ---- stage B2 = fc2T[0..192)[hc*128 .. +128) into lW (swizzled) ----
        {
            v8bf wbuf[12];
            #pragma unroll
            for (int c = 0; c < 12; ++c) {
                int cid = c * 256 + tid;
                int row = cid >> 4, k8 = cid & 15;
                wbuf[c] = *(const v8bf*)(fc2T + (size_t)row * HID + hc * 128 + k8 * 8);
            }
            #pragma unroll
            for (int c = 0; c < 12; ++c) {
                int cid = c * 256 + tid;
                int row = cid >> 4, k8 = cid & 15;
                *(v8bf*)(lW + row * 256 + ((k8 * 16) ^ ((row & 7) << 4))) = wbuf[c];
            }
        }
        __syncthreads();
        // ---- fc2: oacc += lH[128x128] * B2^T (192 cols) ----
        #pragma unroll
        for (int k2 = 0; k2 < 4; ++k2) {
            v8bf pa[4], pb[6];
            #pragma unroll
            for (int i = 0; i < 4; ++i) {
                int ra = wm + i * 16 + lrow;
                pa[i] = *(const v8bf*)(lH + ra * 256 + ((k2 * 64 + lq * 16) ^ ((ra & 7) << 4)));
            }
            #pragma unroll
            for (int j = 0; j < 6; ++j) {
                int rw = wn + j * 16 + lrow;
                pb[j] = *(const v8bf*)(lW + rw * 256 + ((k2 * 64 + lq * 16) ^ ((rw & 7) << 4)));
            }
            #pragma unroll
            for (int i = 0; i < 4; ++i)
            #pragma unroll
            for (int j = 0; j < 6; ++j)
                oacc[i][j] = __builtin_amdgcn_mfma_f32_16x16x32_bf16(pa[i], pb[j], oacc[i][j], 0, 0, 0);
        }
        __syncthreads();   // lH/lW reads done before next hc overwrites
    }
    // ---- epilogue: out = oacc + fc2b + x1 (residual; x1 rows L2-hot) ----
    #pragma unroll
    for (int i = 0; i < 4; ++i)
    #pragma unroll
    for (int j = 0; j < 6; ++j) {
        int col = wn + j * 16 + lrow;
        float bv = fc2b[col];
        #pragma unroll
        for (int r = 0; r < 4; ++r) {
            int row = m0 + wm + i * 16 + lq * 4 + r;
            size_t o = (size_t)row * DIM + col;
            out[o] = oacc[i][j][r] + bv + x1[o];
        }
    }
}

// ---------------------------------------------------------------------------
extern "C" void kernel_launch(void* const* d_in, const int* in_sizes, int n_in,
                              void* d_out, int out_size, void* d_ws, size_t ws_size,
                              hipStream_t stream) {
    const float* x      = (const float*)d_in[0];
    const float* n1g    = (const float*)d_in[1];
    const float* n1b    = (const float*)d_in[2];
    const float* qkv_w  = (const float*)d_in[3];
    const float* qkv_b  = (const float*)d_in[4];
    const float* rpb    = (const float*)d_in[5];
    const float* proj_w = (const float*)d_in[6];
    const float* proj_b = (const float*)d_in[7];
    const float* n2g    = (const float*)d_in[8];
    const float* n2b    = (const float*)d_in[9];
    const float* fc1_w  = (const float*)d_in[10];
    const float* fc1_b  = (const float*)d_in[11];
    const float* fc2_w  = (const float*)d_in[12];
    const float* fc2_b  = (const float*)d_in[13];
    float* outp = (float*)d_out;

    char* ws = (char*)d_ws;
    const size_t SZA = (size_t)MTOT * DIM * 2;      // 38,535,168
    // Layout (~155 MB total):
    //   xw @ 0          : SZA      (ln1 out -> qkv A; attn out -> proj A)
    //   qb @ SZA        : 3*SZA    (q,k,v; dead after attn)
    //   x1 @ SZA        : overlays q/k/v (f32, 2*SZA) after attn
    //   weights @ 4*SZA : 884,736  transposed bf16
    //   btab            : 393,216  bias tables
    __bf16* xw = (__bf16*)ws;
    __bf16* qb = (__bf16*)(ws + SZA);
    float*  x1 = (float*)(ws + SZA);
    char* wbase = ws + 4 * SZA;
    __bf16* qkvT  = (__bf16*)wbase;
    __bf16* projT = qkvT + 576 * 192;
    __bf16* fc1T  = projT + 192 * 192;
    __bf16* fc2T  = fc1T + 768 * 192;
    float*  btab  = (float*)(fc2T + 768 * 192);

    k_transpose<<<(192 * 576 + 255) / 256, 256, 0, stream>>>(qkv_w, qkvT, 192, 576);
    k_transpose<<<(192 * 192 + 255) / 256, 256, 0, stream>>>(proj_w, projT, 192, 192);
    k_transpose<<<(192 * 768 + 255) / 256, 256, 0, stream>>>(fc1_w, fc1T, 192, 768);
    k_transpose<<<(768 * 192 + 255) / 256, 256, 0, stream>>>(fc2_w, fc2T, 768, 192);
    k_bias<<<dim3(4, HEADS), 256, 0, stream>>>(rpb, btab);

    k_ln1win<<<MTOT / 4, 256, 0, stream>>>(x, n1g, n1b, xw);

    // qkv: [M x 192] x [576 x 192]^T -> scatter q/k/v [w,h,t,32]
    k_gemm128<192, 576, 0><<<dim3(MTOT / 128, 5), 256, 0, stream>>>(
        xw, qkvT, qkv_b, qb, nullptr, nullptr, nullptr);

    k_attn_mfma<<<NWIN * HEADS, 64, 0, stream>>>(qb, btab, xw);

    // proj: [M x 192] x [192 x 192]^T -> x1 f32 (image order, +residual)
    k_gemm128<192, 192, 1><<<dim3(MTOT / 128, 2), 256, 0, stream>>>(
        xw, projT, proj_b, nullptr, nullptr, x1, x);

    // fused LN2 + fc1 + GELU + fc2 + residual  (hid stays in LDS)
    k_mlp_fused<<<MTOT / 128, 256, 0, stream>>>(
        x1, n2g, n2b, fc1T, fc1_b, fc2T, fc2_b, outp);
}

// Round 2
// 524.030 us; speedup vs baseline: 1.1544x; 1.1544x over previous
//
#include <hip/hip_runtime.h>
#include <cmath>

typedef __bf16  v8bf  __attribute__((ext_vector_type(8)));
typedef float   v4f   __attribute__((ext_vector_type(4)));

#define HH 56
#define WW2 56
#define SS 3
#define HEADS 6
#define DIM 192
#define HID 768
#define NTOK 49
#define NWIN 2048            // BATCH * 64
#define MTOT (NWIN * NTOK)   // 100352
#define SCALE 0.17677669529663687f

// async global->LDS, 16B per lane. LDS dest must be wave-uniform base + lane*16.
__device__ __forceinline__ void async_cp16(const __bf16* g, __bf16* l) {
    __builtin_amdgcn_global_load_lds(
        (const __attribute__((address_space(1))) void*)g,
        (__attribute__((address_space(3))) void*)l,
        16, 0, 0);
}

// ---------------------------------------------------------------------------
// Weight transpose + f32->bf16 cast: out[n*K + k] = (bf16)in[k*N + n]
// ---------------------------------------------------------------------------
__global__ void k_transpose(const float* __restrict__ in, __bf16* __restrict__ out,
                            int K, int N) {
    int idx = blockIdx.x * 256 + threadIdx.x;
    if (idx >= K * N) return;
    int n = idx / K, k = idx - n * K;
    out[idx] = (__bf16)in[k * N + n];
}

// ---------------------------------------------------------------------------
// Pre-swizzled MLP weights (so k_mlp_fused can stage via global_load_lds with
// a LINEAR LDS dest and still get XOR-swizzled LDS images; guideline 21).
// fc1S: bf16 idx = n*192 + b16*8 + j  holds fc1_w[(8*(b16^(n&7))+j)*768 + n]
//   -> LDS image: row n_local (stride 384B), byte = (k*2) ^ ((n&7)<<4)
// fc2S: bf16 idx = hc*12288 + n*64 + b16*8 + j holds
//       fc2_w[(hc*64 + 8*(b16^(n&7)) + j)*192 + n]
//   -> LDS image: row n (stride 128B), byte = (kc*2) ^ ((n&7)<<4)
// ---------------------------------------------------------------------------
__global__ void k_prep_fc1(const float* __restrict__ w, __bf16* __restrict__ o) {
    int idx = blockIdx.x * 256 + threadIdx.x;
    if (idx >= HID * DIM) return;
    int n = idx / DIM, rem = idx - n * DIM;
    int b16 = rem >> 3, j = rem & 7;
    int k = 8 * (b16 ^ (n & 7)) + j;
    o[idx] = (__bf16)w[k * HID + n];
}

__global__ void k_prep_fc2(const float* __restrict__ w, __bf16* __restrict__ o) {
    int idx = blockIdx.x * 256 + threadIdx.x;
    if (idx >= HID * DIM) return;
    int hc = idx / (DIM * 64);
    int rem = idx - hc * DIM * 64;
    int n = rem >> 6;
    int rem2 = rem & 63;
    int b16 = rem2 >> 3, j = rem2 & 7;
    int k = hc * 64 + 8 * (b16 ^ (n & 7)) + j;
    o[idx] = (__bf16)w[k * DIM + n];
}

// ---------------------------------------------------------------------------
// Precompute bias tables: bias_tab[type][h][m][n], type in {0=interior,
// 1=right-edge, 2=bottom-edge, 3=corner}. Includes rel-pos bias, shift mask,
// and -1e9 padding for cols m>=49.  n-contiguous so attention loads float4.
// ---------------------------------------------------------------------------
__global__ void k_bias(const float* __restrict__ rpb, float* __restrict__ bt) {
    int type = blockIdx.x, h = blockIdx.y;
    for (int idx = threadIdx.x; idx < 4096; idx += 256) {
        int m = idx >> 6, n = idx & 63;
        float v;
        if (m >= 49) v = -1e9f;
        else if (n >= 49) v = 0.f;
        else {
            int ni = n / 7, nj = n % 7, mi = m / 7, mj = m % 7;
            v = rpb[((ni - mi + 6) * 13 + (nj - mj + 6)) * 6 + h];
            int rin = (type & 2) ? ((ni < 4) ? 1 : 2) : 0;
            int rjn = (type & 1) ? ((nj < 4) ? 1 : 2) : 0;
            int rim = (type & 2) ? ((mi < 4) ? 1 : 2) : 0;
            int rjm = (type & 1) ? ((mj < 4) ? 1 : 2) : 0;
            if (rin * 3 + rjn != rim * 3 + rjm) v -= 100.f;
        }
        bt[((size_t)(type * HEADS + h) * 64 + m) * 64 + n] = v;
    }
}

// ---------------------------------------------------------------------------
// LN1 + cyclic shift(-3,-3) + window partition. x f32 -> xw bf16 [w*49+p][c].
// ---------------------------------------------------------------------------
__global__ __launch_bounds__(256) void k_ln1win(const float* __restrict__ x,
                                                const float* __restrict__ g,
                                                const float* __restrict__ bt,
                                                __bf16* __restrict__ xw) {
    int wv = threadIdx.x >> 6, lane = threadIdx.x & 63;
    int t = blockIdx.x * 4 + wv;
    int w = t / NTOK, p = t - w * NTOK;
    int b = w >> 6, wi = w & 63;
    int i = (wi >> 3) * 7 + p / 7;
    int j = (wi & 7) * 7 + p % 7;
    int io = i + SS; if (io >= HH) io -= HH;
    int jo = j + SS; if (jo >= WW2) jo -= WW2;
    const float* src = x + ((size_t)(b * 3136 + io * 56 + jo)) * DIM;
    float v0 = src[lane], v1 = src[lane + 64], v2 = src[lane + 128];
    float s = v0 + v1 + v2, s2 = v0 * v0 + v1 * v1 + v2 * v2;
    #pragma unroll
    for (int off = 1; off < 64; off <<= 1) {
        s  += __shfl_xor(s, off);
        s2 += __shfl_xor(s2, off);
    }
    float mu = s * (1.f / 192.f);
    float rstd = rsqrtf(s2 * (1.f / 192.f) - mu * mu + 1e-5f);
    __bf16* dst = xw + (size_t)t * DIM;
    dst[lane]       = (__bf16)((v0 - mu) * rstd * g[lane]       + bt[lane]);
    dst[lane + 64]  = (__bf16)((v1 - mu) * rstd * g[lane + 64]  + bt[lane + 64]);
    dst[lane + 128] = (__bf16)((v2 - mu) * rstd * g[lane + 128] + bt[lane + 128]);
}

// ---------------------------------------------------------------------------
// 128x128-tile MFMA GEMM: C = A[MxK] * Wt[NxK]^T + bias.
// MODE 0: qkv scatter -> qb/kb/vb [w,h,t,32] bf16 (q scaled).
// MODE 1: proj -> outf = x1 (window-reverse scatter) + xres, f32
// ---------------------------------------------------------------------------
template<int KDIM, int NDIM, int MODE>
__global__ __launch_bounds__(256) void k_gemm128(const __bf16* __restrict__ A,
                                                 const __bf16* __restrict__ Wt,
                                                 const float* __restrict__ bias,
                                                 __bf16* __restrict__ outb,
                                                 const float* __restrict__ x1in,
                                                 float* __restrict__ outf,
                                                 const float* __restrict__ xres) {
    __shared__ __bf16 lA[128 * 32];
    __shared__ __bf16 lB[128 * 32];
    const int tid = threadIdx.x;
    const int m0 = blockIdx.x * 128, n0 = blockIdx.y * 128;
    const int wv = tid >> 6, lane = tid & 63;
    const int wm = (wv >> 1) * 64, wn = (wv & 1) * 64;
    const int lrow = lane & 15, lq = lane >> 4;
    const int grow = tid >> 2, gkc = (tid & 3) * 8;
    v4f acc[4][4] = {};
    for (int kk = 0; kk < KDIM; kk += 32) {
        #pragma unroll
        for (int c = 0; c < 2; c++) {
            int r = grow + c * 64;
            async_cp16(A + (size_t)(m0 + r) * KDIM + kk + gkc, lA + tid * 8 + c * 2048);
            int rb = n0 + r;
            if (NDIM % 128) rb = (rb < NDIM) ? rb : (NDIM - 1);
            async_cp16(Wt + (size_t)rb * KDIM + kk + gkc, lB + tid * 8 + c * 2048);
        }
        __syncthreads();
        v8bf af[4], bf[4];
        #pragma unroll
        for (int i = 0; i < 4; i++) {
            af[i] = *(const v8bf*)(lA + (wm + i * 16 + lrow) * 32 + lq * 8);
            bf[i] = *(const v8bf*)(lB + (wn + i * 16 + lrow) * 32 + lq * 8);
        }
        #pragma unroll
        for (int i = 0; i < 4; i++)
        #pragma unroll
        for (int j = 0; j < 4; j++)
            acc[i][j] = __builtin_amdgcn_mfma_f32_16x16x32_bf16(af[i], bf[j], acc[i][j], 0, 0, 0);
        __syncthreads();
    }
    #pragma unroll
    for (int i = 0; i < 4; i++)
    #pragma unroll
    for (int j = 0; j < 4; j++) {
        int col = n0 + wn + j * 16 + lrow;
        if (NDIM % 128 && col >= NDIM) continue;
        float bv = bias[col];
        #pragma unroll
        for (int r = 0; r < 4; r++) {
            int row = m0 + wm + i * 16 + lq * 4 + r;
            float v = acc[i][j][r] + bv;
            if (MODE == 0) {
                __bf16* kbp = outb + (size_t)MTOT * DIM;
                __bf16* vbp = kbp + (size_t)MTOT * DIM;
                int which = col / DIM, rem = col - which * DIM;
                int hh = rem >> 5, d = rem & 31;
                int w = row / NTOK, p = row - w * NTOK;
                size_t off = ((size_t)(w * HEADS + hh) * NTOK + p) * 32 + d;
                if (which == 0)      outb[off] = (__bf16)(v * SCALE);
                else if (which == 1) kbp[off] = (__bf16)v;
                else                 vbp[off] = (__bf16)v;
            } else {  // proj: window-reverse + unshift + residual
                int w = row / NTOK, p = row - w * NTOK;
                int bimg = w >> 6, wi = w & 63;
                int ii = (wi >> 3) * 7 + p / 7;
                int jj = (wi & 7) * 7 + p % 7;
                int io = ii + SS; if (io >= HH) io -= HH;
                int jo = jj + SS; if (jo >= WW2) jo -= WW2;
                size_t o = ((size_t)(bimg * 3136 + io * 56 + jo)) * DIM + col;
                outf[o] = v + xres[o];
            }
        }
    }
}

// ---------------------------------------------------------------------------
// MFMA windowed attention: one wave per (window, head), 64-thread blocks.
// ---------------------------------------------------------------------------
__global__ __launch_bounds__(64) void k_attn_mfma(const __bf16* __restrict__ qb,
                                                  const float* __restrict__ bias_tab,
                                                  __bf16* __restrict__ ao) {
    __shared__ __bf16 Pl[64 * 72];
    __shared__ __bf16 VTl[32 * 72];
    const __bf16* kb = qb + (size_t)MTOT * DIM;
    const __bf16* vb = kb + (size_t)MTOT * DIM;
    int wh = blockIdx.x;
    int w = wh / HEADS, h = wh - w * HEADS;
    int lane = threadIdx.x & 63;
    int c = lane & 15, q = lane >> 4;
    const size_t base = (size_t)wh * (NTOK * 32);

    for (int idx = lane; idx < 32 * 16; idx += 64)
        VTl[(idx >> 4) * 72 + 48 + (idx & 15)] = (__bf16)0.f;
    #pragma unroll
    for (int it = 0; it < 4; it++) {
        int idx = it * 64 + lane;
        if (idx < NTOK * 4) {
            int t = idx >> 2, d0 = (idx & 3) * 8;
            v8bf vv = *(const v8bf*)(vb + base + t * 32 + d0);
            #pragma unroll
            for (int ii = 0; ii < 8; ii++) VTl[(d0 + ii) * 72 + t] = vv[ii];
        }
    }
    v8bf af[4], bf[4];
    #pragma unroll
    for (int rt = 0; rt < 4; rt++) {
        int t = rt * 16 + c; t = (t > 48) ? 48 : t;
        af[rt] = *(const v8bf*)(qb + base + t * 32 + q * 8);
        bf[rt] = *(const v8bf*)(kb + base + t * 32 + q * 8);
    }
    v4f S[4][4] = {};
    #pragma unroll
    for (int rt = 0; rt < 4; rt++)
    #pragma unroll
    for (int ct = 0; ct < 4; ct++)
        S[rt][ct] = __builtin_amdgcn_mfma_f32_16x16x32_bf16(af[rt], bf[ct], S[rt][ct], 0, 0, 0);
    int wi = w & 63;
    int type = (((wi >> 3) == 7) ? 2 : 0) + (((wi & 7) == 7) ? 1 : 0);
    const float* bt = bias_tab + (size_t)(type * HEADS + h) * 4096;
    #pragma unroll
    for (int rt = 0; rt < 4; rt++)
    #pragma unroll
    for (int ct = 0; ct < 4; ct++) {
        v4f bv = *(const v4f*)(bt + (ct * 16 + c) * 64 + rt * 16 + q * 4);
        S[rt][ct] += bv;
    }
    v4f mx4[4], inv4[4];
    #pragma unroll
    for (int rt = 0; rt < 4; rt++) {
        v4f m;
        #pragma unroll
        for (int r = 0; r < 4; r++)
            m[r] = fmaxf(fmaxf(S[rt][0][r], S[rt][1][r]), fmaxf(S[rt][2][r], S[rt][3][r]));
        #pragma unroll
        for (int off = 1; off < 16; off <<= 1) {
            #pragma unroll
            for (int r = 0; r < 4; r++) m[r] = fmaxf(m[r], __shfl_xor(m[r], off));
        }
        mx4[rt] = m;
    }
    #pragma unroll
    for (int rt = 0; rt < 4; rt++) {
        v4f dsum = {};
        #pragma unroll
        for (int ct = 0; ct < 4; ct++) {
            #pragma unroll
            for (int r = 0; r < 4; r++) {
                float e = __expf(S[rt][ct][r] - mx4[rt][r]);
                dsum[r] += e;
                Pl[(rt * 16 + q * 4 + r) * 72 + ct * 16 + c] = (__bf16)e;
            }
        }
        #pragma unroll
        for (int off = 1; off < 16; off <<= 1) {
            #pragma unroll
            for (int r = 0; r < 4; r++) dsum[r] += __shfl_xor(dsum[r], off);
        }
        #pragma unroll
        for (int r = 0; r < 4; r++) inv4[rt][r] = 1.f / dsum[r];
    }
    __syncthreads();
    v4f O[4][2] = {};
    #pragma unroll
    for (int k2 = 0; k2 < 2; k2++) {
        v8bf pa[4], pb[2];
        #pragma unroll
        for (int rt = 0; rt < 4; rt++)
            pa[rt] = *(const v8bf*)(Pl + (rt * 16 + c) * 72 + k2 * 32 + q * 8);
        #pragma unroll
        for (int ct = 0; ct < 2; ct++)
            pb[ct] = *(const v8bf*)(VTl + (ct * 16 + c) * 72 + k2 * 32 + q * 8);
        #pragma unroll
        for (int rt = 0; rt < 4; rt++)
        #pragma unroll
        for (int ct = 0; ct < 2; ct++)
            O[rt][ct] = __builtin_amdgcn_mfma_f32_16x16x32_bf16(pa[rt], pb[ct], O[rt][ct], 0, 0, 0);
    }
    __bf16* aop = ao + (size_t)(w * NTOK) * DIM + h * 32;
    #pragma unroll
    for (int rt = 0; rt < 4; rt++)
    #pragma unroll
    for (int r = 0; r < 4; r++) {
        int row = rt * 16 + q * 4 + r;
        if (row < NTOK) {
            #pragma unroll
            for (int ct = 0; ct < 2; ct++)
                aop[(size_t)row * DIM + ct * 16 + c] = (__bf16)(O[rt][ct][r] * inv4[rt][r]);
        }
    }
}

// ---------------------------------------------------------------------------
// Fused MLP: LN2 + fc1 + GELU + fc2 + residual. hid stays in LDS.
// BM=64 rows/block, hidden chunk HC=64 (12 chunks).
// LDS = 57,344 B -> 2 blocks/CU (8 waves/CU, 2/SIMD) for latency hiding:
//   aT: [64][384B]  LN2 output, XOR-swizzled (byte ^= (row&7)<<4)
//   lW: 24,576 B    fc1 chunk [64][384B] / fc2 chunk [192][128B], staged via
//                   global_load_lds from PRE-SWIZZLED fc1S/fc2S (linear dest)
//   lH: [64][128B]  GELU(hid chunk), XOR-swizzled
// All ds_read_b128 fragment reads are <=2-way bank aliased (free).
// ---------------------------------------------------------------------------
__global__ __launch_bounds__(256, 2) void k_mlp_fused(
        const float* __restrict__ x1,
        const float* __restrict__ n2g, const float* __restrict__ n2b,
        const __bf16* __restrict__ fc1S, const float* __restrict__ fc1b,
        const __bf16* __restrict__ fc2S, const float* __restrict__ fc2b,
        float* __restrict__ out) {
    __shared__ __align__(16) char sm[57344];
    char* aT = sm;                // 24576
    char* lW = sm + 24576;        // 24576
    char* lH = sm + 49152;        //  8192
    const int tid = threadIdx.x;
    const int wv = tid >> 6, lane = tid & 63;
    const int lrow = lane & 15, lq = lane >> 4;
    const int m0 = blockIdx.x * 64;

    // prefetch fc1 chunk 0 while LN runs
    #pragma unroll
    for (int p = 0; p < 6; ++p)
        async_cp16(fc1S + p * 2048 + tid * 8, (__bf16*)lW + p * 2048 + tid * 8);

    // ---- Phase 0: LN2 of 64 rows into aT (bf16, swizzled); 16 rows/wave ----
    {
        float g0 = n2g[lane], g1 = n2g[lane + 64], g2 = n2g[lane + 128];
        float b0 = n2b[lane], b1 = n2b[lane + 64], b2 = n2b[lane + 128];
        #pragma unroll 4
        for (int it = 0; it < 16; ++it) {
            int row = wv * 16 + it;
            const float* src = x1 + (size_t)(m0 + row) * DIM;
            float v0 = src[lane], v1 = src[lane + 64], v2 = src[lane + 128];
            float s = v0 + v1 + v2, s2 = v0 * v0 + v1 * v1 + v2 * v2;
            #pragma unroll
            for (int off = 1; off < 64; off <<= 1) {
                s  += __shfl_xor(s, off);
                s2 += __shfl_xor(s2, off);
            }
            float mu = s * (1.f / 192.f);
            float rstd = rsqrtf(s2 * (1.f / 192.f) - mu * mu + 1e-5f);
            char* rb = aT + row * 384;
            int xo = (row & 7) << 4;
            *(__bf16*)(rb + ((lane * 2)       ^ xo)) = (__bf16)((v0 - mu) * rstd * g0 + b0);
            *(__bf16*)(rb + ((lane * 2 + 128) ^ xo)) = (__bf16)((v1 - mu) * rstd * g1 + b1);
            *(__bf16*)(rb + ((lane * 2 + 256) ^ xo)) = (__bf16)((v2 - mu) * rstd * g2 + b2);
        }
    }
    __syncthreads();   // aT ready; fc1 chunk 0 landed (vmcnt drained)

    const int wm = (wv >> 1) * 32;   // row-tile base
    const int wc1 = (wv & 1) * 32;   // fc1 col base within 64-chunk
    const int wn  = (wv & 1) * 96;   // fc2 col base (192 total)
    v4f oacc[2][6] = {};

    for (int hc = 0; hc < 12; ++hc) {
        // ---- fc1: hid_chunk[64][64] = aT[64x192] * W1^T ----
        v4f hacc[2][2] = {};
        __builtin_amdgcn_s_setprio(1);
        #pragma unroll
        for (int ks = 0; ks < 6; ++ks) {
            v8bf af[2], bw[2];
            #pragma unroll
            for (int i = 0; i < 2; ++i) {
                int ra = wm + i * 16 + lrow;
                af[i] = *(const v8bf*)(aT + ra * 384 + ((ks * 64 + lq * 16) ^ ((ra & 7) << 4)));
                int rw = wc1 + i * 16 + lrow;
                bw[i] = *(const v8bf*)(lW + rw * 384 + ((ks * 64 + lq * 16) ^ ((rw & 7) << 4)));
            }
            #pragma unroll
            for (int i = 0; i < 2; ++i)
            #pragma unroll
            for (int j = 0; j < 2; ++j)
                hacc[i][j] = __builtin_amdgcn_mfma_f32_16x16x32_bf16(af[i], bw[j], hacc[i][j], 0, 0, 0);
        }
        __builtin_amdgcn_s_setprio(0);
        // ---- bias + exact GELU -> lH (swizzled) ----
        #pragma unroll
        for (int i = 0; i < 2; ++i)
        #pragma unroll
        for (int j = 0; j < 2; ++j) {
            float bv = fc1b[hc * 64 + wc1 + j * 16 + lrow];
            #pragma unroll
            for (int r = 0; r < 4; ++r) {
                int row = wm + i * 16 + lq * 4 + r;
                int col = wc1 + j * 16 + lrow;
                float hv = hacc[i][j][r] + bv;
                float ge = 0.5f * hv * (1.f + erff(hv * 0.70710678118654752f));
                *(__bf16*)(lH + row * 128 + ((col * 2) ^ ((row & 7) << 4))) = (__bf16)ge;
            }
        }
        __syncthreads();   // lH visible; all lW (fc1) reads complete
        // ---- stage fc2 chunk into lW (async, pre-swizzled source) ----
        {
            const __bf16* src = fc2S + (size_t)hc * (192 * 64);
            #pragma unroll
            for (int p = 0; p < 6; ++p)
                async_cp16(src + p * 2048 + tid * 8, (__bf16*)lW + p * 2048 + tid * 8);
        }
        __syncthreads();   // fc2 weights landed
        // ---- fc2: oacc += lH[64x64] * W2^T (192 cols) ----
        __builtin_amdgcn_s_setprio(1);
        #pragma unroll
        for (int k2 = 0; k2 < 2; ++k2) {
            v8bf pa[2], pb[6];
            #pragma unroll
            for (int i = 0; i < 2; ++i) {
                int ra = wm + i * 16 + lrow;
                pa[i] = *(const v8bf*)(lH + ra * 128 + ((k2 * 64 + lq * 16) ^ ((ra & 7) << 4)));
            }
            #pragma unroll
            for (int j = 0; j < 6; ++j) {
                int rw = wn + j * 16 + lrow;
                pb[j] = *(const v8bf*)(lW + rw * 128 + ((k2 * 64 + lq * 16) ^ ((rw & 7) << 4)));
            }
            #pragma unroll
            for (int i = 0; i < 2; ++i)
            #pragma unroll
            for (int j = 0; j < 6; ++j)
                oacc[i][j] = __builtin_amdgcn_mfma_f32_16x16x32_bf16(pa[i], pb[j], oacc[i][j], 0, 0, 0);
        }
        __builtin_amdgcn_s_setprio(0);
        __syncthreads();   // lH/lW reads done
        // ---- stage next fc1 chunk into lW (async) ----
        if (hc < 11) {
            const __bf16* src = fc1S + (size_t)(hc + 1) * (64 * 192);
            #pragma unroll
            for (int p = 0; p < 6; ++p)
                async_cp16(src + p * 2048 + tid * 8, (__bf16*)lW + p * 2048 + tid * 8);
            __syncthreads();   // fc1 weights landed
        }
    }
    // ---- epilogue: out = oacc + fc2b + x1 (residual) ----
    #pragma unroll
    for (int i = 0; i < 2; ++i)
    #pragma unroll
    for (int j = 0; j < 6; ++j) {
        int col = wn + j * 16 + lrow;
        float bv = fc2b[col];
        #pragma unroll
        for (int r = 0; r < 4; ++r) {
            int row = m0 + wm + i * 16 + lq * 4 + r;
            size_t o = (size_t)row * DIM + col;
            out[o] = oacc[i][j][r] + bv + x1[o];
        }
    }
}

// ---------------------------------------------------------------------------
extern "C" void kernel_launch(void* const* d_in, const int* in_sizes, int n_in,
                              void* d_out, int out_size, void* d_ws, size_t ws_size,
                              hipStream_t stream) {
    const float* x      = (const float*)d_in[0];
    const float* n1g    = (const float*)d_in[1];
    const float* n1b    = (const float*)d_in[2];
    const float* qkv_w  = (const float*)d_in[3];
    const float* qkv_b  = (const float*)d_in[4];
    const float* rpb    = (const float*)d_in[5];
    const float* proj_w = (const float*)d_in[6];
    const float* proj_b = (const float*)d_in[7];
    const float* n2g    = (const float*)d_in[8];
    const float* n2b    = (const float*)d_in[9];
    const float* fc1_w  = (const float*)d_in[10];
    const float* fc1_b  = (const float*)d_in[11];
    const float* fc2_w  = (const float*)d_in[12];
    const float* fc2_b  = (const float*)d_in[13];
    float* outp = (float*)d_out;

    char* ws = (char*)d_ws;
    const size_t SZA = (size_t)MTOT * DIM * 2;      // 38,535,168
    // Layout (~155 MB total):
    //   xw @ 0          : SZA      (ln1 out -> qkv A; attn out -> proj A)
    //   qb @ SZA        : 3*SZA    (q,k,v; dead after attn)
    //   x1 @ SZA        : overlays q/k/v (f32, 2*SZA) after attn
    //   weights @ 4*SZA : transposed / pre-swizzled bf16
    __bf16* xw = (__bf16*)ws;
    __bf16* qb = (__bf16*)(ws + SZA);
    float*  x1 = (float*)(ws + SZA);
    char* wbase = ws + 4 * SZA;
    __bf16* qkvT  = (__bf16*)wbase;
    __bf16* projT = qkvT + 576 * 192;
    __bf16* fc1S  = projT + 192 * 192;
    __bf16* fc2S  = fc1S + 768 * 192;
    float*  btab  = (float*)(fc2S + 768 * 192);

    k_transpose<<<(192 * 576 + 255) / 256, 256, 0, stream>>>(qkv_w, qkvT, 192, 576);
    k_transpose<<<(192 * 192 + 255) / 256, 256, 0, stream>>>(proj_w, projT, 192, 192);
    k_prep_fc1<<<(768 * 192 + 255) / 256, 256, 0, stream>>>(fc1_w, fc1S);
    k_prep_fc2<<<(768 * 192 + 255) / 256, 256, 0, stream>>>(fc2_w, fc2S);
    k_bias<<<dim3(4, HEADS), 256, 0, stream>>>(rpb, btab);

    k_ln1win<<<MTOT / 4, 256, 0, stream>>>(x, n1g, n1b, xw);

    // qkv: [M x 192] x [576 x 192]^T -> scatter q/k/v [w,h,t,32]
    k_gemm128<192, 576, 0><<<dim3(MTOT / 128, 5), 256, 0, stream>>>(
        xw, qkvT, qkv_b, qb, nullptr, nullptr, nullptr);

    k_attn_mfma<<<NWIN * HEADS, 64, 0, stream>>>(qb, btab, xw);

    // proj: [M x 192] x [192 x 192]^T -> x1 f32 (image order, +residual)
    k_gemm128<192, 192, 1><<<dim3(MTOT / 128, 2), 256, 0, stream>>>(
        xw, projT, proj_b, nullptr, nullptr, x1, x);

    // fused LN2 + fc1 + GELU + fc2 + residual  (hid stays in LDS)
    k_mlp_fused<<<MTOT / 64, 256, 0, stream>>>(
        x1, n2g, n2b, fc1S, fc1_b, fc2S, fc2_b, outp);
}

// Round 3
// 477.770 us; speedup vs baseline: 1.2662x; 1.0968x over previous
//
#include <hip/hip_runtime.h>
#include <cmath>

typedef __bf16  v8bf  __attribute__((ext_vector_type(8)));
typedef float   v4f   __attribute__((ext_vector_type(4)));

#define HH 56
#define WW2 56
#define SS 3
#define HEADS 6
#define DIM 192
#define HID 768
#define NTOK 49
#define NWIN 2048            // BATCH * 64
#define MTOT (NWIN * NTOK)   // 100352
#define SCALE 0.17677669529663687f

// async global->LDS, 16B per lane. LDS dest must be wave-uniform base + lane*16.
__device__ __forceinline__ void async_cp16(const __bf16* g, __bf16* l) {
    __builtin_amdgcn_global_load_lds(
        (const __attribute__((address_space(1))) void*)g,
        (__attribute__((address_space(3))) void*)l,
        16, 0, 0);
}

// raw workgroup barrier (no implicit vmcnt(0) drain, unlike __syncthreads)
__device__ __forceinline__ void wg_barrier() {
    __builtin_amdgcn_sched_barrier(0);
    __builtin_amdgcn_s_barrier();
    __builtin_amdgcn_sched_barrier(0);
}
#define WAIT_LGKM0() asm volatile("s_waitcnt lgkmcnt(0)" ::: "memory")
#define WAIT_VM(n)   asm volatile("s_waitcnt vmcnt(" #n ")" ::: "memory")

// fast exact-accuracy GELU: erf via Abramowitz-Stegun 7.1.26 (|err|<1.5e-7,
// far below bf16 rounding).  ~16 VALU ops vs ~50 for libm erff.
__device__ __forceinline__ float fast_gelu(float x) {
    float z = fabsf(x) * 0.70710678118654752f;
    float t = __builtin_amdgcn_rcpf(1.f + 0.3275911f * z);
    float poly = t * (0.254829592f + t * (-0.284496736f +
                 t * (1.421413741f + t * (-1.453152027f + t * 1.061405429f))));
    float er = 1.f - poly * __expf(-z * z);
    er = (x < 0.f) ? -er : er;
    return 0.5f * x * (1.f + er);
}

// ---------------------------------------------------------------------------
// Weight transpose + f32->bf16 cast: out[n*K + k] = (bf16)in[k*N + n]
// ---------------------------------------------------------------------------
__global__ void k_transpose(const float* __restrict__ in, __bf16* __restrict__ out,
                            int K, int N) {
    int idx = blockIdx.x * 256 + threadIdx.x;
    if (idx >= K * N) return;
    int n = idx / K, k = idx - n * K;
    out[idx] = (__bf16)in[k * N + n];
}

// ---------------------------------------------------------------------------
// Pre-swizzled MLP weights (so k_mlp_fused can stage via global_load_lds with
// a LINEAR LDS dest and still get XOR-swizzled LDS images; guideline 21).
// fc1S: bf16 idx = n*192 + b16*8 + j  holds fc1_w[(8*(b16^(n&7))+j)*768 + n]
//   -> LDS image: row n_local (stride 384B), byte = (k*2) ^ ((n&7)<<4)
// fc2S: bf16 idx = hc*12288 + n*64 + b16*8 + j holds
//       fc2_w[(hc*64 + 8*(b16^(n&7)) + j)*192 + n]
//   -> LDS image: row n (stride 128B), byte = (kc*2) ^ ((n&7)<<4)
// ---------------------------------------------------------------------------
__global__ void k_prep_fc1(const float* __restrict__ w, __bf16* __restrict__ o) {
    int idx = blockIdx.x * 256 + threadIdx.x;
    if (idx >= HID * DIM) return;
    int n = idx / DIM, rem = idx - n * DIM;
    int b16 = rem >> 3, j = rem & 7;
    int k = 8 * (b16 ^ (n & 7)) + j;
    o[idx] = (__bf16)w[k * HID + n];
}

__global__ void k_prep_fc2(const float* __restrict__ w, __bf16* __restrict__ o) {
    int idx = blockIdx.x * 256 + threadIdx.x;
    if (idx >= HID * DIM) return;
    int hc = idx / (DIM * 64);
    int rem = idx - hc * DIM * 64;
    int n = rem >> 6;
    int rem2 = rem & 63;
    int b16 = rem2 >> 3, j = rem2 & 7;
    int k = hc * 64 + 8 * (b16 ^ (n & 7)) + j;
    o[idx] = (__bf16)w[k * DIM + n];
}

// ---------------------------------------------------------------------------
// Precompute bias tables: bias_tab[type][h][m][n], type in {0=interior,
// 1=right-edge, 2=bottom-edge, 3=corner}. Includes rel-pos bias, shift mask,
// and -1e9 padding for cols m>=49.  n-contiguous so attention loads float4.
// ---------------------------------------------------------------------------
__global__ void k_bias(const float* __restrict__ rpb, float* __restrict__ bt) {
    int type = blockIdx.x, h = blockIdx.y;
    for (int idx = threadIdx.x; idx < 4096; idx += 256) {
        int m = idx >> 6, n = idx & 63;
        float v;
        if (m >= 49) v = -1e9f;
        else if (n >= 49) v = 0.f;
        else {
            int ni = n / 7, nj = n % 7, mi = m / 7, mj = m % 7;
            v = rpb[((ni - mi + 6) * 13 + (nj - mj + 6)) * 6 + h];
            int rin = (type & 2) ? ((ni < 4) ? 1 : 2) : 0;
            int rjn = (type & 1) ? ((nj < 4) ? 1 : 2) : 0;
            int rim = (type & 2) ? ((mi < 4) ? 1 : 2) : 0;
            int rjm = (type & 1) ? ((mj < 4) ? 1 : 2) : 0;
            if (rin * 3 + rjn != rim * 3 + rjm) v -= 100.f;
        }
        bt[((size_t)(type * HEADS + h) * 64 + m) * 64 + n] = v;
    }
}

// ---------------------------------------------------------------------------
// LN1 + cyclic shift(-3,-3) + window partition. x f32 -> xw bf16 [w*49+p][c].
// ---------------------------------------------------------------------------
__global__ __launch_bounds__(256) void k_ln1win(const float* __restrict__ x,
                                                const float* __restrict__ g,
                                                const float* __restrict__ bt,
                                                __bf16* __restrict__ xw) {
    int wv = threadIdx.x >> 6, lane = threadIdx.x & 63;
    int t = blockIdx.x * 4 + wv;
    int w = t / NTOK, p = t - w * NTOK;
    int b = w >> 6, wi = w & 63;
    int i = (wi >> 3) * 7 + p / 7;
    int j = (wi & 7) * 7 + p % 7;
    int io = i + SS; if (io >= HH) io -= HH;
    int jo = j + SS; if (jo >= WW2) jo -= WW2;
    const float* src = x + ((size_t)(b * 3136 + io * 56 + jo)) * DIM;
    float v0 = src[lane], v1 = src[lane + 64], v2 = src[lane + 128];
    float s = v0 + v1 + v2, s2 = v0 * v0 + v1 * v1 + v2 * v2;
    #pragma unroll
    for (int off = 1; off < 64; off <<= 1) {
        s  += __shfl_xor(s, off);
        s2 += __shfl_xor(s2, off);
    }
    float mu = s * (1.f / 192.f);
    float rstd = rsqrtf(s2 * (1.f / 192.f) - mu * mu + 1e-5f);
    __bf16* dst = xw + (size_t)t * DIM;
    dst[lane]       = (__bf16)((v0 - mu) * rstd * g[lane]       + bt[lane]);
    dst[lane + 64]  = (__bf16)((v1 - mu) * rstd * g[lane + 64]  + bt[lane + 64]);
    dst[lane + 128] = (__bf16)((v2 - mu) * rstd * g[lane + 128] + bt[lane + 128]);
}

// ---------------------------------------------------------------------------
// 128x128-tile MFMA GEMM: C = A[MxK] * Wt[NxK]^T + bias.
// MODE 0: qkv scatter -> qb/kb/vb [w,h,t,32] bf16 (q scaled).
// MODE 1: proj -> outf = x1 (window-reverse scatter) + xres, f32
// ---------------------------------------------------------------------------
template<int KDIM, int NDIM, int MODE>
__global__ __launch_bounds__(256) void k_gemm128(const __bf16* __restrict__ A,
                                                 const __bf16* __restrict__ Wt,
                                                 const float* __restrict__ bias,
                                                 __bf16* __restrict__ outb,
                                                 const float* __restrict__ x1in,
                                                 float* __restrict__ outf,
                                                 const float* __restrict__ xres) {
    __shared__ __bf16 lA[128 * 32];
    __shared__ __bf16 lB[128 * 32];
    const int tid = threadIdx.x;
    const int m0 = blockIdx.x * 128, n0 = blockIdx.y * 128;
    const int wv = tid >> 6, lane = tid & 63;
    const int wm = (wv >> 1) * 64, wn = (wv & 1) * 64;
    const int lrow = lane & 15, lq = lane >> 4;
    const int grow = tid >> 2, gkc = (tid & 3) * 8;
    v4f acc[4][4] = {};
    for (int kk = 0; kk < KDIM; kk += 32) {
        #pragma unroll
        for (int c = 0; c < 2; c++) {
            int r = grow + c * 64;
            async_cp16(A + (size_t)(m0 + r) * KDIM + kk + gkc, lA + tid * 8 + c * 2048);
            int rb = n0 + r;
            if (NDIM % 128) rb = (rb < NDIM) ? rb : (NDIM - 1);
            async_cp16(Wt + (size_t)rb * KDIM + kk + gkc, lB + tid * 8 + c * 2048);
        }
        __syncthreads();
        v8bf af[4], bf[4];
        #pragma unroll
        for (int i = 0; i < 4; i++) {
            af[i] = *(const v8bf*)(lA + (wm + i * 16 + lrow) * 32 + lq * 8);
            bf[i] = *(const v8bf*)(lB + (wn + i * 16 + lrow) * 32 + lq * 8);
        }
        #pragma unroll
        for (int i = 0; i < 4; i++)
        #pragma unroll
        for (int j = 0; j < 4; j++)
            acc[i][j] = __builtin_amdgcn_mfma_f32_16x16x32_bf16(af[i], bf[j], acc[i][j], 0, 0, 0);
        __syncthreads();
    }
    #pragma unroll
    for (int i = 0; i < 4; i++)
    #pragma unroll
    for (int j = 0; j < 4; j++) {
        int col = n0 + wn + j * 16 + lrow;
        if (NDIM % 128 && col >= NDIM) continue;
        float bv = bias[col];
        #pragma unroll
        for (int r = 0; r < 4; r++) {
            int row = m0 + wm + i * 16 + lq * 4 + r;
            float v = acc[i][j][r] + bv;
            if (MODE == 0) {
                __bf16* kbp = outb + (size_t)MTOT * DIM;
                __bf16* vbp = kbp + (size_t)MTOT * DIM;
                int which = col / DIM, rem = col - which * DIM;
                int hh = rem >> 5, d = rem & 31;
                int w = row / NTOK, p = row - w * NTOK;
                size_t off = ((size_t)(w * HEADS + hh) * NTOK + p) * 32 + d;
                if (which == 0)      outb[off] = (__bf16)(v * SCALE);
                else if (which == 1) kbp[off] = (__bf16)v;
                else                 vbp[off] = (__bf16)v;
            } else {  // proj: window-reverse + unshift + residual
                int w = row / NTOK, p = row - w * NTOK;
                int bimg = w >> 6, wi = w & 63;
                int ii = (wi >> 3) * 7 + p / 7;
                int jj = (wi & 7) * 7 + p % 7;
                int io = ii + SS; if (io >= HH) io -= HH;
                int jo = jj + SS; if (jo >= WW2) jo -= WW2;
                size_t o = ((size_t)(bimg * 3136 + io * 56 + jo)) * DIM + col;
                outf[o] = v + xres[o];
            }
        }
    }
}

// ---------------------------------------------------------------------------
// MFMA windowed attention: one wave per (window, head), 64-thread blocks.
// ---------------------------------------------------------------------------
__global__ __launch_bounds__(64) void k_attn_mfma(const __bf16* __restrict__ qb,
                                                  const float* __restrict__ bias_tab,
                                                  __bf16* __restrict__ ao) {
    __shared__ __bf16 Pl[64 * 72];
    __shared__ __bf16 VTl[32 * 72];
    const __bf16* kb = qb + (size_t)MTOT * DIM;
    const __bf16* vb = kb + (size_t)MTOT * DIM;
    int wh = blockIdx.x;
    int w = wh / HEADS, h = wh - w * HEADS;
    int lane = threadIdx.x & 63;
    int c = lane & 15, q = lane >> 4;
    const size_t base = (size_t)wh * (NTOK * 32);

    for (int idx = lane; idx < 32 * 16; idx += 64)
        VTl[(idx >> 4) * 72 + 48 + (idx & 15)] = (__bf16)0.f;
    #pragma unroll
    for (int it = 0; it < 4; it++) {
        int idx = it * 64 + lane;
        if (idx < NTOK * 4) {
            int t = idx >> 2, d0 = (idx & 3) * 8;
            v8bf vv = *(const v8bf*)(vb + base + t * 32 + d0);
            #pragma unroll
            for (int ii = 0; ii < 8; ii++) VTl[(d0 + ii) * 72 + t] = vv[ii];
        }
    }
    v8bf af[4], bf[4];
    #pragma unroll
    for (int rt = 0; rt < 4; rt++) {
        int t = rt * 16 + c; t = (t > 48) ? 48 : t;
        af[rt] = *(const v8bf*)(qb + base + t * 32 + q * 8);
        bf[rt] = *(const v8bf*)(kb + base + t * 32 + q * 8);
    }
    v4f S[4][4] = {};
    #pragma unroll
    for (int rt = 0; rt < 4; rt++)
    #pragma unroll
    for (int ct = 0; ct < 4; ct++)
        S[rt][ct] = __builtin_amdgcn_mfma_f32_16x16x32_bf16(af[rt], bf[ct], S[rt][ct], 0, 0, 0);
    int wi = w & 63;
    int type = (((wi >> 3) == 7) ? 2 : 0) + (((wi & 7) == 7) ? 1 : 0);
    const float* bt = bias_tab + (size_t)(type * HEADS + h) * 4096;
    #pragma unroll
    for (int rt = 0; rt < 4; rt++)
    #pragma unroll
    for (int ct = 0; ct < 4; ct++) {
        v4f bv = *(const v4f*)(bt + (ct * 16 + c) * 64 + rt * 16 + q * 4);
        S[rt][ct] += bv;
    }
    v4f mx4[4], inv4[4];
    #pragma unroll
    for (int rt = 0; rt < 4; rt++) {
        v4f m;
        #pragma unroll
        for (int r = 0; r < 4; r++)
            m[r] = fmaxf(fmaxf(S[rt][0][r], S[rt][1][r]), fmaxf(S[rt][2][r], S[rt][3][r]));
        #pragma unroll
        for (int off = 1; off < 16; off <<= 1) {
            #pragma unroll
            for (int r = 0; r < 4; r++) m[r] = fmaxf(m[r], __shfl_xor(m[r], off));
        }
        mx4[rt] = m;
    }
    #pragma unroll
    for (int rt = 0; rt < 4; rt++) {
        v4f dsum = {};
        #pragma unroll
        for (int ct = 0; ct < 4; ct++) {
            #pragma unroll
            for (int r = 0; r < 4; r++) {
                float e = __expf(S[rt][ct][r] - mx4[rt][r]);
                dsum[r] += e;
                Pl[(rt * 16 + q * 4 + r) * 72 + ct * 16 + c] = (__bf16)e;
            }
        }
        #pragma unroll
        for (int off = 1; off < 16; off <<= 1) {
            #pragma unroll
            for (int r = 0; r < 4; r++) dsum[r] += __shfl_xor(dsum[r], off);
        }
        #pragma unroll
        for (int r = 0; r < 4; r++) inv4[rt][r] = 1.f / dsum[r];
    }
    __syncthreads();
    v4f O[4][2] = {};
    #pragma unroll
    for (int k2 = 0; k2 < 2; k2++) {
        v8bf pa[4], pb[2];
        #pragma unroll
        for (int rt = 0; rt < 4; rt++)
            pa[rt] = *(const v8bf*)(Pl + (rt * 16 + c) * 72 + k2 * 32 + q * 8);
        #pragma unroll
        for (int ct = 0; ct < 2; ct++)
            pb[ct] = *(const v8bf*)(VTl + (ct * 16 + c) * 72 + k2 * 32 + q * 8);
        #pragma unroll
        for (int rt = 0; rt < 4; rt++)
        #pragma unroll
        for (int ct = 0; ct < 2; ct++)
            O[rt][ct] = __builtin_amdgcn_mfma_f32_16x16x32_bf16(pa[rt], pb[ct], O[rt][ct], 0, 0, 0);
    }
    __bf16* aop = ao + (size_t)(w * NTOK) * DIM + h * 32;
    #pragma unroll
    for (int rt = 0; rt < 4; rt++)
    #pragma unroll
    for (int r = 0; r < 4; r++) {
        int row = rt * 16 + q * 4 + r;
        if (row < NTOK) {
            #pragma unroll
            for (int ct = 0; ct < 2; ct++)
                aop[(size_t)row * DIM + ct * 16 + c] = (__bf16)(O[rt][ct][r] * inv4[rt][r]);
        }
    }
}

// ---------------------------------------------------------------------------
// Fused MLP v3: LN2 + fc1 + GELU + fc2 + residual. BM=64, HC=64 (12 chunks).
//
// Pipeline (T3/T4): raw s_barrier + counted s_waitcnt vmcnt(6) — weight
// stages are issued one phase ahead and land under compute; NO vmcnt(0)
// drain inside the loop.  A-operand (LN2 output) lives in 48 VGPRs (read
// once from LDS, then that space is recycled as the fc2 weight buffer).
// Both biases staged to LDS in the prologue so the loop body has ZERO
// vmem ops other than the 6 counted global_load_lds per stage.
//
// LDS 61,184 B -> 2 blocks/CU:
//   bufX 24,576 : aT (LN2 image) then fc2 weight chunks
//   bufY 24,576 : fc1 weight chunks
//   lH    8,192 : GELU(hid chunk), XOR-swizzled
//   lB1/lB2     : fc1/fc2 bias (f32)
// ---------------------------------------------------------------------------
__global__ __launch_bounds__(256, 2) void k_mlp_fused(
        const float* __restrict__ x1,
        const float* __restrict__ n2g, const float* __restrict__ n2b,
        const __bf16* __restrict__ fc1S, const float* __restrict__ fc1b,
        const __bf16* __restrict__ fc2S, const float* __restrict__ fc2b,
        float* __restrict__ out) {
    __shared__ __align__(16) char sm[61184];
    char* bufX = sm;                     // 24576
    char* bufY = sm + 24576;             // 24576
    char* lH   = sm + 49152;             //  8192
    float* lB1 = (float*)(sm + 57344);   //  3072 (768 f32)
    float* lB2 = (float*)(sm + 60416);   //   768 (192 f32)
    const int tid = threadIdx.x;
    const int wv = tid >> 6, lane = tid & 63;
    const int lrow = lane & 15, lq = lane >> 4;
    const int m0 = blockIdx.x * 64;

    // prefetch W1 chunk 0 into bufY (lands while LN runs; LN's own vmem
    // consumption waits drain it — oldest-first vmcnt semantics)
    #pragma unroll
    for (int p = 0; p < 6; ++p)
        async_cp16(fc1S + p * 2048 + tid * 8, (__bf16*)bufY + p * 2048 + tid * 8);

    // stage biases to LDS (loop body must stay free of extra vmem ops)
    #pragma unroll
    for (int p = 0; p < 3; ++p) lB1[p * 256 + tid] = fc1b[p * 256 + tid];
    if (tid < 192) lB2[tid] = fc2b[tid];

    // ---- Phase 0: LN2 of 64 rows into bufX (bf16, swizzled); 16 rows/wave
    {
        float g0 = n2g[lane], g1 = n2g[lane + 64], g2 = n2g[lane + 128];
        float b0 = n2b[lane], b1 = n2b[lane + 64], b2 = n2b[lane + 128];
        #pragma unroll 4
        for (int it = 0; it < 16; ++it) {
            int row = wv * 16 + it;
            const float* src = x1 + (size_t)(m0 + row) * DIM;
            float v0 = src[lane], v1 = src[lane + 64], v2 = src[lane + 128];
            float s = v0 + v1 + v2, s2 = v0 * v0 + v1 * v1 + v2 * v2;
            #pragma unroll
            for (int off = 1; off < 64; off <<= 1) {
                s  += __shfl_xor(s, off);
                s2 += __shfl_xor(s2, off);
            }
            float mu = s * (1.f / 192.f);
            float rstd = rsqrtf(s2 * (1.f / 192.f) - mu * mu + 1e-5f);
            char* rb = bufX + row * 384;
            int xo = (row & 7) << 4;
            *(__bf16*)(rb + ((lane * 2)       ^ xo)) = (__bf16)((v0 - mu) * rstd * g0 + b0);
            *(__bf16*)(rb + ((lane * 2 + 128) ^ xo)) = (__bf16)((v1 - mu) * rstd * g1 + b1);
            *(__bf16*)(rb + ((lane * 2 + 256) ^ xo)) = (__bf16)((v2 - mu) * rstd * g2 + b2);
        }
    }
    WAIT_LGKM0();
    wg_barrier();        // aT + biases visible to all waves; W1[0] landed

    // ---- A fragments -> registers; bufX then recycled as fc2 W buffer ----
    const int wm  = (wv >> 1) * 32;   // row-tile base
    const int wc1 = (wv & 1) * 32;    // fc1 col base within 64-chunk
    const int wn  = (wv & 1) * 96;    // fc2 col base (192 total)
    v8bf afr[2][6];
    #pragma unroll
    for (int i = 0; i < 2; ++i) {
        int ra = wm + i * 16 + lrow;
        #pragma unroll
        for (int ks = 0; ks < 6; ++ks)
            afr[i][ks] = *(const v8bf*)(bufX + ra * 384 + ((ks * 64 + lq * 16) ^ ((ra & 7) << 4)));
    }
    WAIT_LGKM0();        // frags in VGPRs before DMA overwrites bufX
    wg_barrier();

    // issue W2 chunk 0 into bufX (lands under fc1[0] compute)
    #pragma unroll
    for (int p = 0; p < 6; ++p)
        async_cp16(fc2S + p * 2048 + tid * 8, (__bf16*)bufX + p * 2048 + tid * 8);

    v4f oacc[2][6] = {};
    for (int hc = 0; hc < 12; ++hc) {
        int hn = hc + 1; if (hn == 12) hn = 0;   // wrapped: keeps waits uniform
        // ---- fc1: hid_chunk[64][64] = afr * W1[hc](bufY)^T ----
        v4f hacc[2][2] = {};
        __builtin_amdgcn_s_setprio(1);
        #pragma unroll
        for (int ks = 0; ks < 6; ++ks) {
            v8bf bw[2];
            #pragma unroll
            for (int j = 0; j < 2; ++j) {
                int rw = wc1 + j * 16 + lrow;
                bw[j] = *(const v8bf*)(bufY + rw * 384 + ((ks * 64 + lq * 16) ^ ((rw & 7) << 4)));
            }
            #pragma unroll
            for (int i = 0; i < 2; ++i)
            #pragma unroll
            for (int j = 0; j < 2; ++j)
                hacc[i][j] = __builtin_amdgcn_mfma_f32_16x16x32_bf16(afr[i][ks], bw[j], hacc[i][j], 0, 0, 0);
        }
        __builtin_amdgcn_s_setprio(0);
        // ---- bias + fast GELU -> lH (swizzled) ----
        #pragma unroll
        for (int i = 0; i < 2; ++i)
        #pragma unroll
        for (int j = 0; j < 2; ++j) {
            float bv = lB1[hc * 64 + wc1 + j * 16 + lrow];
            #pragma unroll
            for (int r = 0; r < 4; ++r) {
                int row = wm + i * 16 + lq * 4 + r;
                int col = wc1 + j * 16 + lrow;
                float hv = hacc[i][j][r] + bv;
                *(__bf16*)(lH + row * 128 + ((col * 2) ^ ((row & 7) << 4))) = (__bf16)fast_gelu(hv);
            }
        }
        WAIT_LGKM0();
        wg_barrier();                      // lH visible; bufY reads done everywhere
        {   // issue W1[hn] -> bufY (lands under fc2 compute)
            const __bf16* s1 = fc1S + (size_t)hn * (64 * 192);
            #pragma unroll
            for (int p = 0; p < 6; ++p)
                async_cp16(s1 + p * 2048 + tid * 8, (__bf16*)bufY + p * 2048 + tid * 8);
        }
        WAIT_VM(6);                        // W2[hc] (older 6) landed; W1[hn] in flight
        wg_barrier();                      // -> all waves' W2[hc] landed
        // ---- fc2: oacc += lH[64x64] * W2[hc](bufX)^T (192 cols) ----
        __builtin_amdgcn_s_setprio(1);
        #pragma unroll
        for (int k2 = 0; k2 < 2; ++k2) {
            v8bf pa[2], pb[6];
            #pragma unroll
            for (int i = 0; i < 2; ++i) {
                int ra = wm + i * 16 + lrow;
                pa[i] = *(const v8bf*)(lH + ra * 128 + ((k2 * 64 + lq * 16) ^ ((ra & 7) << 4)));
            }
            #pragma unroll
            for (int j = 0; j < 6; ++j) {
                int rw = wn + j * 16 + lrow;
                pb[j] = *(const v8bf*)(bufX + rw * 128 + ((k2 * 64 + lq * 16) ^ ((rw & 7) << 4)));
            }
            #pragma unroll
            for (int i = 0; i < 2; ++i)
            #pragma unroll
            for (int j = 0; j < 6; ++j)
                oacc[i][j] = __builtin_amdgcn_mfma_f32_16x16x32_bf16(pa[i], pb[j], oacc[i][j], 0, 0, 0);
        }
        __builtin_amdgcn_s_setprio(0);
        WAIT_LGKM0();
        wg_barrier();                      // bufX/lH reads done everywhere
        {   // issue W2[hn] -> bufX (lands under next fc1 compute)
            const __bf16* s2 = fc2S + (size_t)hn * (192 * 64);
            #pragma unroll
            for (int p = 0; p < 6; ++p)
                async_cp16(s2 + p * 2048 + tid * 8, (__bf16*)bufX + p * 2048 + tid * 8);
        }
        WAIT_VM(6);                        // W1[hn] (older 6) landed; W2[hn] in flight
        wg_barrier();
    }
    WAIT_VM(0);   // drain wrapped redundant loads before LDS teardown
    // ---- epilogue: out = oacc + fc2b + x1 (residual) ----
    #pragma unroll
    for (int i = 0; i < 2; ++i)
    #pragma unroll
    for (int j = 0; j < 6; ++j) {
        int col = wn + j * 16 + lrow;
        float bv = lB2[col];
        #pragma unroll
        for (int r = 0; r < 4; ++r) {
            int row = m0 + wm + i * 16 + lq * 4 + r;
            size_t o = (size_t)row * DIM + col;
            out[o] = oacc[i][j][r] + bv + x1[o];
        }
    }
}

// ---------------------------------------------------------------------------
extern "C" void kernel_launch(void* const* d_in, const int* in_sizes, int n_in,
                              void* d_out, int out_size, void* d_ws, size_t ws_size,
                              hipStream_t stream) {
    const float* x      = (const float*)d_in[0];
    const float* n1g    = (const float*)d_in[1];
    const float* n1b    = (const float*)d_in[2];
    const float* qkv_w  = (const float*)d_in[3];
    const float* qkv_b  = (const float*)d_in[4];
    const float* rpb    = (const float*)d_in[5];
    const float* proj_w = (const float*)d_in[6];
    const float* proj_b = (const float*)d_in[7];
    const float* n2g    = (const float*)d_in[8];
    const float* n2b    = (const float*)d_in[9];
    const float* fc1_w  = (const float*)d_in[10];
    const float* fc1_b  = (const float*)d_in[11];
    const float* fc2_w  = (const float*)d_in[12];
    const float* fc2_b  = (const float*)d_in[13];
    float* outp = (float*)d_out;

    char* ws = (char*)d_ws;
    const size_t SZA = (size_t)MTOT * DIM * 2;      // 38,535,168
    // Layout (~155 MB total):
    //   xw @ 0          : SZA      (ln1 out -> qkv A; attn out -> proj A)
    //   qb @ SZA        : 3*SZA    (q,k,v; dead after attn)
    //   x1 @ SZA        : overlays q/k/v (f32, 2*SZA) after attn
    //   weights @ 4*SZA : transposed / pre-swizzled bf16
    __bf16* xw = (__bf16*)ws;
    __bf16* qb = (__bf16*)(ws + SZA);
    float*  x1 = (float*)(ws + SZA);
    char* wbase = ws + 4 * SZA;
    __bf16* qkvT  = (__bf16*)wbase;
    __bf16* projT = qkvT + 576 * 192;
    __bf16* fc1S  = projT + 192 * 192;
    __bf16* fc2S  = fc1S + 768 * 192;
    float*  btab  = (float*)(fc2S + 768 * 192);

    k_transpose<<<(192 * 576 + 255) / 256, 256, 0, stream>>>(qkv_w, qkvT, 192, 576);
    k_transpose<<<(192 * 192 + 255) / 256, 256, 0, stream>>>(proj_w, projT, 192, 192);
    k_prep_fc1<<<(768 * 192 + 255) / 256, 256, 0, stream>>>(fc1_w, fc1S);
    k_prep_fc2<<<(768 * 192 + 255) / 256, 256, 0, stream>>>(fc2_w, fc2S);
    k_bias<<<dim3(4, HEADS), 256, 0, stream>>>(rpb, btab);

    k_ln1win<<<MTOT / 4, 256, 0, stream>>>(x, n1g, n1b, xw);

    // qkv: [M x 192] x [576 x 192]^T -> scatter q/k/v [w,h,t,32]
    k_gemm128<192, 576, 0><<<dim3(MTOT / 128, 5), 256, 0, stream>>>(
        xw, qkvT, qkv_b, qb, nullptr, nullptr, nullptr);

    k_attn_mfma<<<NWIN * HEADS, 64, 0, stream>>>(qb, btab, xw);

    // proj: [M x 192] x [192 x 192]^T -> x1 f32 (image order, +residual)
    k_gemm128<192, 192, 1><<<dim3(MTOT / 128, 2), 256, 0, stream>>>(
        xw, projT, proj_b, nullptr, nullptr, x1, x);

    // fused LN2 + fc1 + GELU + fc2 + residual  (hid stays in LDS)
    k_mlp_fused<<<MTOT / 64, 256, 0, stream>>>(
        x1, n2g, n2b, fc1S, fc1_b, fc2S, fc2_b, outp);
}